// Round 2
// 166.242 us; speedup vs baseline: 1.0030x; 1.0030x over previous
//
#include <hip/hip_runtime.h>
#include <math.h>

// Problem constants (fixed by setup_inputs)
constexpr int N_ = 8, C_ = 256, F_ = 16, WH_ = 784;
constexpr int CH_STRIDE = F_ * WH_;        // 12544 floats between channels
constexpr int COUT_SZ = N_ * F_ * WH_;     // 100352 floats (c output)

__device__ inline float wave_reduce_sum(float v) {
#pragma unroll
  for (int o = 32; o > 0; o >>= 1) v += __shfl_down(v, o, 64);
  return v;
}
__device__ inline float wave_reduce_max(float v) {
#pragma unroll
  for (int o = 32; o > 0; o >>= 1) v = fmaxf(v, __shfl_down(v, o, 64));
  return v;
}

// ---------------- Kernel 1: compatibility map c ----------------
// grid 256 = (nf << 1 | ph): block computes c[nf, ph*392 .. ph*392+392).
// Thread layout: q = tid>>7 (8 channel-groups of 32 ch), p4 = tid&127
// (float4-position slot within the half; active when p4 < 98).
// Splitting positions (not channels) across blocks keeps each c value
// complete in one block -> no cross-block reduction, full-GPU grid.
__global__ __launch_bounds__(1024) void c_kernel(
    const float* __restrict__ l, const float* __restrict__ g,
    const float* __restrict__ w, float* __restrict__ out) {
  __shared__ float w_s[C_];
  __shared__ float red_s[16];
  __shared__ float gb_s;
  __shared__ float4 ps[8][98];  // per-channel-group float4 partials

  const int bid = blockIdx.x;
  const int nf = bid >> 1;
  const int ph = bid & 1;
  const int n = nf >> 4;
  const int f = nf & 15;
  const int tid = threadIdx.x;
  const int q = tid >> 7;
  const int p4 = tid & 127;

  if (tid < C_) w_s[tid] = w[tid];

  // gb = sum_c g[n,c] * w[c]
  float gv = (tid < C_) ? g[n * C_ + tid] * w[tid] : 0.f;
  gv = wave_reduce_sum(gv);
  if ((tid & 63) == 0) red_s[tid >> 6] = gv;
  __syncthreads();  // also makes w_s visible
  if (tid == 0) {
    float s = 0.f;
#pragma unroll
    for (int i = 0; i < 16; ++i) s += red_s[i];
    gb_s = s;
  }
  __syncthreads();

  if (p4 < 98) {
    const float* lp = l + ((size_t)(n * C_ + (q << 5)) * F_ + f) * WH_ +
                      ph * 392 + (p4 << 2);
    float4 acc = make_float4(0.f, 0.f, 0.f, 0.f);
#pragma unroll 8
    for (int c = 0; c < 32; ++c) {
      const float4 lv =
          *reinterpret_cast<const float4*>(lp + (size_t)c * CH_STRIDE);
      const float wc = w_s[(q << 5) + c];
      acc.x = fmaf(lv.x, wc, acc.x);
      acc.y = fmaf(lv.y, wc, acc.y);
      acc.z = fmaf(lv.z, wc, acc.z);
      acc.w = fmaf(lv.w, wc, acc.w);
    }
    ps[q][p4] = acc;
  }
  __syncthreads();

  if (tid < 98) {
    float4 s = ps[0][tid];
#pragma unroll
    for (int i = 1; i < 8; ++i) {
      const float4 t = ps[i][tid];
      s.x += t.x; s.y += t.y; s.z += t.z; s.w += t.w;
    }
    const float gb = gb_s;
    s.x += gb; s.y += gb; s.z += gb; s.w += gb;
    *reinterpret_cast<float4*>(
        &out[(size_t)nf * WH_ + ph * 392 + (tid << 2)]) = s;
  }
}

// ---------------- Kernel 2: softmax + attention pooling ----------------
// grid 256 = (nf << 1 | chalf): block re-reads the complete c row (written
// by K1, L2/L3-hot), recomputes the softmax (redundant 2x per nf, trivial),
// then pools its 128 channels. Wave wv handles channels chalf*128 + wv + 16i.
__global__ __launch_bounds__(1024) void pool_kernel(
    const float* __restrict__ l, float* __restrict__ out) {
  __shared__ float e_s[WH_];
  __shared__ float red_s[16];
  __shared__ float bc_s;

  const int bid = blockIdx.x;
  const int nf = bid >> 1;
  const int ch = bid & 1;
  const int n = nf >> 4;
  const int f = nf & 15;
  const int tid = threadIdx.x;
  const int lane = tid & 63;
  const int wv = tid >> 6;

  float cv = -3.4e38f;
  if (tid < WH_) cv = out[(size_t)nf * WH_ + tid];  // c from K1

  float m = wave_reduce_max(cv);
  if (lane == 0) red_s[wv] = m;
  __syncthreads();
  if (tid == 0) {
    float mm = red_s[0];
#pragma unroll
    for (int i = 1; i < 16; ++i) mm = fmaxf(mm, red_s[i]);
    bc_s = mm;
  }
  __syncthreads();
  const float cmax = bc_s;

  float e = 0.f;
  if (tid < WH_) {
    e = expf(cv - cmax);
    e_s[tid] = e;
  }
  float s = wave_reduce_sum(e);
  __syncthreads();  // tid0 done reading red_s (max phase), cmax consumed
  if (lane == 0) red_s[wv] = s;
  __syncthreads();
  if (tid == 0) {
    float ss = 0.f;
#pragma unroll
    for (int i = 0; i < 16; ++i) ss += red_s[i];
    bc_s = 1.f / ss;
  }
  __syncthreads();
  const float inv_sum = bc_s;  // fold normalization into final store

  // Preload this wave's slice of e_s into registers (shared by all channels).
  const int p0 = lane << 2;
  const float4 ew0 = *reinterpret_cast<const float4*>(&e_s[p0]);
  const float4 ew1 = *reinterpret_cast<const float4*>(&e_s[p0 + 256]);
  const float4 ew2 = *reinterpret_cast<const float4*>(&e_s[p0 + 512]);
  float4 ew3 = make_float4(0.f, 0.f, 0.f, 0.f);
  if (lane < 4) ew3 = *reinterpret_cast<const float4*>(&e_s[768 + p0]);

#pragma unroll 1
  for (int i = 0; i < 8; ++i) {
    const int c = (ch << 7) + wv + (i << 4);
    const float* bp = l + ((size_t)(n * C_ + c) * F_ + f) * WH_;
    float4 lv0 = *reinterpret_cast<const float4*>(bp + p0);
    float4 lv1 = *reinterpret_cast<const float4*>(bp + p0 + 256);
    float4 lv2 = *reinterpret_cast<const float4*>(bp + p0 + 512);
    float4 lv3 = make_float4(0.f, 0.f, 0.f, 0.f);
    if (lane < 4) lv3 = *reinterpret_cast<const float4*>(bp + 768 + p0);

    float acc = 0.f;
    acc = fmaf(lv0.x, ew0.x, acc); acc = fmaf(lv0.y, ew0.y, acc);
    acc = fmaf(lv0.z, ew0.z, acc); acc = fmaf(lv0.w, ew0.w, acc);
    acc = fmaf(lv1.x, ew1.x, acc); acc = fmaf(lv1.y, ew1.y, acc);
    acc = fmaf(lv1.z, ew1.z, acc); acc = fmaf(lv1.w, ew1.w, acc);
    acc = fmaf(lv2.x, ew2.x, acc); acc = fmaf(lv2.y, ew2.y, acc);
    acc = fmaf(lv2.z, ew2.z, acc); acc = fmaf(lv2.w, ew2.w, acc);
    acc = fmaf(lv3.x, ew3.x, acc); acc = fmaf(lv3.y, ew3.y, acc);
    acc = fmaf(lv3.z, ew3.z, acc); acc = fmaf(lv3.w, ew3.w, acc);

    acc = wave_reduce_sum(acc);
    if (lane == 0)
      out[COUT_SZ + (size_t)(n * C_ + c) * F_ + f] = acc * inv_sum;
  }
}

extern "C" void kernel_launch(void* const* d_in, const int* in_sizes, int n_in,
                              void* d_out, int out_size, void* d_ws,
                              size_t ws_size, hipStream_t stream) {
  const float* l = (const float*)d_in[0];
  const float* g = (const float*)d_in[1];
  const float* w = (const float*)d_in[2];
  float* out = (float*)d_out;
  // K1 writes the c section of out; K2 (stream-ordered after) reads it back,
  // recomputes the softmax per block, and writes the g_out section.
  c_kernel<<<dim3(2 * N_ * F_), dim3(1024), 0, stream>>>(l, g, w, out);
  pool_kernel<<<dim3(2 * N_ * F_), dim3(1024), 0, stream>>>(l, out);
}